// Round 4
// baseline (392.731 us; speedup 1.0000x reference)
//
#include <hip/hip_runtime.h>

#define BATCH 8
#define ROWS  2048
#define WIDTH 4096
#define COLS  4096
#define KB    1024   // WIDTH / 4 (gating blocks along k)
#define CB    1024   // COLS  / 4 (gating blocks along c)
#define RCH   64     // rows per colsum block

typedef float f32x4 __attribute__((ext_vector_type(4)));

__device__ __forceinline__ f32x4 ntload4(const f32x4* p) {
    return __builtin_nontemporal_load(p);
}
__device__ __forceinline__ float ntloadf(const float* p) {
    return __builtin_nontemporal_load(p);
}

// ---------------------------------------------------------------------------
// Kernel 1 (round-1 strip pattern, NT loads): xs[b,k] = sum_r X[b,r,k].
// grid = (4, 8, 32) = 1024 blocks; atomics into zeroed xs.
// ---------------------------------------------------------------------------
__global__ __launch_bounds__(256) void colsum_kernel(const f32x4* __restrict__ X,
                                                     float* __restrict__ xs) {
    const int k4 = blockIdx.x * 256 + threadIdx.x;  // k/4 in [0,1024)
    const int b  = blockIdx.y;
    const int r0 = blockIdx.z * RCH;

    const f32x4* p = X + (size_t)(b * ROWS + r0) * (WIDTH / 4) + k4;
    float ax = 0.f, ay = 0.f, az = 0.f, aw = 0.f;
#pragma unroll 8
    for (int r = 0; r < RCH; ++r) {
        f32x4 v = ntload4(p + (size_t)r * (WIDTH / 4));
        ax += v.x; ay += v.y; az += v.z; aw += v.w;
    }
    float* dst = xs + (size_t)b * WIDTH + 4 * k4;
    atomicAdd(dst + 0, ax);
    atomicAdd(dst + 1, ay);
    atomicAdd(dst + 2, az);
    atomicAdd(dst + 3, aw);
}

// ---------------------------------------------------------------------------
// Kernel 2 (round-1 form + NT loads + last-block finalize):
//   acc = sum_b G[b,kb,cb] * sum_{j<4} xs[b,4kb+j] * W4[4kb+j, cb]
// Block partials -> blocksum; the LAST block (device-scope ticket) reduces
// all 4096 partials and writes out[0] = s*s. grid = (4, 1024).
// ---------------------------------------------------------------------------
__global__ __launch_bounds__(256) void gated_reduce_kernel(const float* __restrict__ W,
                                                           const float* __restrict__ G,
                                                           const float* __restrict__ xs,
                                                           float* __restrict__ blocksum,
                                                           unsigned* __restrict__ ticket,
                                                           float* __restrict__ out) {
    const int cb = blockIdx.x * 256 + threadIdx.x;  // [0, 1024)
    const int kb = blockIdx.y;                      // [0, 1024)

    const f32x4* Wv = (const f32x4*)W;  // W row k: f32x4 index k*CB + cb
    float w4[4];
#pragma unroll
    for (int j = 0; j < 4; ++j) {
        f32x4 w = ntload4(&Wv[(size_t)(4 * kb + j) * CB + cb]);
        w4[j] = (w.x + w.y) + (w.z + w.w);
    }

    float acc = 0.f;
#pragma unroll
    for (int b = 0; b < BATCH; ++b) {
        float inner = 0.f;
#pragma unroll
        for (int j = 0; j < 4; ++j)
            inner += xs[b * WIDTH + 4 * kb + j] * w4[j];  // block-uniform, cached
        acc += ntloadf(&G[((size_t)b * KB + kb) * CB + cb]) * inner;
    }

    __shared__ float red[256];
    red[threadIdx.x] = acc;
    __syncthreads();
    for (int o = 128; o > 0; o >>= 1) {
        if (threadIdx.x < o) red[threadIdx.x] += red[threadIdx.x + o];
        __syncthreads();
    }

    const int nblocks = gridDim.x * gridDim.y;  // 4096
    const int bid     = blockIdx.y * gridDim.x + blockIdx.x;
    __shared__ bool amLast;
    if (threadIdx.x == 0) {
        blocksum[bid] = red[0];
        __threadfence();  // release partial before ticket
        unsigned prev = __hip_atomic_fetch_add(ticket, 1u, __ATOMIC_ACQ_REL,
                                               __HIP_MEMORY_SCOPE_AGENT);
        amLast = (prev == (unsigned)(nblocks - 1));
    }
    __syncthreads();

    if (amLast) {  // block-uniform branch
        __threadfence();  // acquire all partials
        float a = 0.f;
        for (int i = threadIdx.x; i < nblocks; i += 256) a += blocksum[i];
        red[threadIdx.x] = a;
        __syncthreads();
        for (int o = 128; o > 0; o >>= 1) {
            if (threadIdx.x < o) red[threadIdx.x] += red[threadIdx.x + o];
            __syncthreads();
        }
        if (threadIdx.x == 0) {
            float s = red[0];
            out[0] = s * s;
        }
    }
}

extern "C" void kernel_launch(void* const* d_in, const int* in_sizes, int n_in,
                              void* d_out, int out_size, void* d_ws, size_t ws_size,
                              hipStream_t stream) {
    const float* X = (const float*)d_in[0];  // (8, 2048, 4096)
    const float* W = (const float*)d_in[1];  // (4096, 4096)
    const float* G = (const float*)d_in[2];  // (8, 1024, 1024)
    float* out = (float*)d_out;              // scalar

    float*    xs       = (float*)d_ws;                 // 32768 floats (atomics)
    unsigned* ticket   = (unsigned*)(xs + BATCH * WIDTH);  // 1 word
    float*    blocksum = xs + BATCH * WIDTH + 8;       // 4096 floats (overwritten)

    // zero atomic targets (xs) + ticket every call — deterministic
    hipMemsetAsync(d_ws, 0, (size_t)(BATCH * WIDTH + 8) * sizeof(float), stream);

    dim3 g1(WIDTH / 4 / 256, BATCH, ROWS / RCH);
    colsum_kernel<<<g1, 256, 0, stream>>>((const f32x4*)X, xs);

    dim3 g2(CB / 256, KB);
    gated_reduce_kernel<<<g2, 256, 0, stream>>>(W, G, xs, blocksum, ticket, out);
}